// Round 1
// baseline (43.085 us; speedup 1.0000x reference)
//
#include <hip/hip_runtime.h>
#include <math.h>

// Problem constants (derived from in_sizes at launch where possible).
#define HEADS 4
#define CDIM 128
#define HDIM 512   // HEADS*CDIM
#define FEAT 128
#define CAPSLOTS 1024  // max in-degree we handle (expected ~8)

// ---------------- Kernel A: find edges with dst == target ----------------
__global__ void scan_edges_kernel(const int* __restrict__ ei, int E,
                                  const int* __restrict__ tgt_p,
                                  int* __restrict__ count,
                                  int* __restrict__ srcList, int cap) {
    int tgt = *tgt_p;
    int i = blockIdx.x * blockDim.x + threadIdx.x;
    if (i < E) {
        int d = ei[E + i];          // edge_index[1][i]
        if (d == tgt) {
            int pos = atomicAdd(count, 1);
            if (pos < cap) srcList[pos] = ei[i];   // edge_index[0][i]
        }
    }
}

// ---------------- Kernel B: per source node: feature -> h -> a ----------------
// slot in [0, cnt): srcList nodes; slot == cnt: the target (self-loop).
__global__ void node_kernel(const float* __restrict__ des, const float* __restrict__ tw,
                            const float* __restrict__ npr, const float* __restrict__ cpr,
                            const float* __restrict__ Wd, const float* __restrict__ bd,
                            const float* __restrict__ Wt, const float* __restrict__ bt,
                            const float* __restrict__ Wn, const float* __restrict__ bn,
                            const float* __restrict__ Wc, const float* __restrict__ bc,
                            const float* __restrict__ Wg,
                            const float* __restrict__ att_src, const float* __restrict__ att_dst,
                            const int* __restrict__ tgt_p, const int* __restrict__ count, int cap,
                            const int* __restrict__ srcList,
                            float* __restrict__ aS, float* __restrict__ aD,
                            float* __restrict__ h_all) {
    __shared__ float sdes[768];
    __shared__ float stw[768];
    __shared__ float snp[5];
    __shared__ float scp;
    __shared__ float sfeat[FEAT];
    __shared__ float sh[HDIM];

    int cnt = min(*count, cap);
    int tgt = *tgt_p;

    for (int slot = blockIdx.x; slot <= cnt; slot += gridDim.x) {
        int node = (slot == cnt) ? tgt : srcList[slot];

        // stage input rows into LDS (coalesced)
        for (int k = threadIdx.x; k < 768; k += blockDim.x) {
            sdes[k] = des[(size_t)node * 768 + k];
            stw[k]  = tw [(size_t)node * 768 + k];
        }
        if (threadIdx.x < 5) snp[threadIdx.x] = npr[node * 5 + threadIdx.x];
        if (threadIdx.x == 5) scp = cpr[node];
        __syncthreads();

        // feature = concat(lrelu(des@Wd+bd), lrelu(tw@Wt+bt), lrelu(np@Wn+bn), lrelu(cp@Wc+bc))
        int j = threadIdx.x;
        if (j < 32) {
            float acc = bd[j];
            for (int k = 0; k < 768; ++k) acc = fmaf(sdes[k], Wd[k * 32 + j], acc);
            sfeat[j] = acc > 0.f ? acc : 0.01f * acc;
        } else if (j < 64) {
            int jj = j - 32;
            float acc = bt[jj];
            for (int k = 0; k < 768; ++k) acc = fmaf(stw[k], Wt[k * 32 + jj], acc);
            sfeat[j] = acc > 0.f ? acc : 0.01f * acc;
        } else if (j < 96) {
            int jj = j - 64;
            float acc = bn[jj];
            for (int k = 0; k < 5; ++k) acc = fmaf(snp[k], Wn[k * 32 + jj], acc);
            sfeat[j] = acc > 0.f ? acc : 0.01f * acc;
        } else if (j < 128) {
            int jj = j - 96;
            float acc = fmaf(scp, Wc[jj], bc[jj]);
            sfeat[j] = acc > 0.f ? acc : 0.01f * acc;
        }
        __syncthreads();

        // h = feature @ Wg  (128 x 512), coalesced W reads across threads
        for (int o = threadIdx.x; o < HDIM; o += blockDim.x) {
            float acc = 0.f;
            for (int k = 0; k < FEAT; ++k) acc = fmaf(sfeat[k], Wg[k * HDIM + o], acc);
            sh[o] = acc;
            h_all[(size_t)slot * HDIM + o] = acc;
        }
        __syncthreads();

        // per-head attention logits
        if (threadIdx.x < HEADS) {
            int hd = threadIdx.x;
            float acc = 0.f;
            for (int c = 0; c < CDIM; ++c)
                acc = fmaf(sh[hd * CDIM + c], att_src[hd * CDIM + c], acc);
            aS[slot * HEADS + hd] = acc;
            if (slot == cnt) {
                float accd = 0.f;
                for (int c = 0; c < CDIM; ++c)
                    accd = fmaf(sh[hd * CDIM + c], att_dst[hd * CDIM + c], accd);
                aD[hd] = accd;
            }
        }
        __syncthreads();   // protect LDS before next slot iteration
    }
}

// ---------------- Kernel C: softmax-aggregate + head-mean + MLP ----------------
__global__ void finalize_kernel(const float* __restrict__ x,
                                const float* __restrict__ bgat,
                                const float* __restrict__ Wo1, const float* __restrict__ bo1,
                                const float* __restrict__ Wo2, const float* __restrict__ bo2,
                                const int* __restrict__ count, int cap,
                                const float* __restrict__ aS, const float* __restrict__ aD,
                                const float* __restrict__ h_all,
                                float* __restrict__ out) {
    __shared__ float sout[HDIM];
    __shared__ float scomb[136];
    __shared__ float shmid[64];

    int cnt = min(*count, cap);
    int M = cnt + 1;                  // edges into target + self-loop
    int tid = threadIdx.x;            // blockDim = 512
    int hd = tid >> 7;
    int c  = tid & 127;

    float adv = aD[hd];
    // pass 1: per-head max (stable softmax), redundantly per thread (M is tiny)
    float m = -INFINITY;
    for (int s = 0; s < M; ++s) {
        float e = aS[s * HEADS + hd] + adv;
        e = e > 0.f ? e : 0.2f * e;   // leaky_relu slope 0.2
        m = fmaxf(m, e);
    }
    // pass 2: denom + weighted sum of h
    float denom = 0.f, acc = 0.f;
    for (int s = 0; s < M; ++s) {
        float e = aS[s * HEADS + hd] + adv;
        e = e > 0.f ? e : 0.2f * e;
        float ex = expf(e - m);
        denom += ex;
        acc = fmaf(ex, h_all[(size_t)s * HDIM + hd * CDIM + c], acc);
    }
    sout[tid] = acc / denom;
    __syncthreads();

    // head mean + b_gat, then concat with x
    if (tid < 128) {
        float g = (sout[tid] + sout[128 + tid] + sout[256 + tid] + sout[384 + tid]) * 0.25f
                  + bgat[tid];
        scomb[tid] = g;
    } else if (tid < 136) {
        scomb[tid] = x[tid - 128];
    }
    __syncthreads();

    // hmid = relu(combined @ Wo1 + bo1)   (136 -> 64)
    if (tid < 64) {
        float a = bo1[tid];
        for (int k = 0; k < 136; ++k) a = fmaf(scomb[k], Wo1[k * 64 + tid], a);
        shmid[tid] = a > 0.f ? a : 0.f;
    }
    __syncthreads();

    // out = hmid @ Wo2 + bo2   (64 -> 5)
    if (tid < 5) {
        float a = bo2[tid];
        for (int k = 0; k < 64; ++k) a = fmaf(shmid[k], Wo2[k * 5 + tid], a);
        out[tid] = a;
    }
}

extern "C" void kernel_launch(void* const* d_in, const int* in_sizes, int n_in,
                              void* d_out, int out_size, void* d_ws, size_t ws_size,
                              hipStream_t stream) {
    const float* x    = (const float*)d_in[0];
    const float* des  = (const float*)d_in[1];
    const float* tw   = (const float*)d_in[2];
    const float* npr  = (const float*)d_in[3];
    const float* cpr  = (const float*)d_in[4];
    const int*   ei   = (const int*)d_in[5];     // [2, E] flat: row0 = src, row1 = dst
    const int*   tgt  = (const int*)d_in[6];
    const float* Wd   = (const float*)d_in[7];   const float* bd  = (const float*)d_in[8];
    const float* Wt   = (const float*)d_in[9];   const float* bt  = (const float*)d_in[10];
    const float* Wn   = (const float*)d_in[11];  const float* bn  = (const float*)d_in[12];
    const float* Wc   = (const float*)d_in[13];  const float* bc  = (const float*)d_in[14];
    const float* Wg   = (const float*)d_in[15];
    const float* as_  = (const float*)d_in[16];  const float* ad_ = (const float*)d_in[17];
    const float* bg   = (const float*)d_in[18];
    const float* Wo1  = (const float*)d_in[19];  const float* bo1 = (const float*)d_in[20];
    const float* Wo2  = (const float*)d_in[21];  const float* bo2 = (const float*)d_in[22];

    const int E = in_sizes[5] / 2;

    // workspace layout (bytes):
    //   0      : int count
    //   256    : int srcList[CAPSLOTS]
    //   4352   : float aS[(CAPSLOTS+1) * 4]
    //   20992  : float aD[4]
    //   21504  : float h_all[(CAPSLOTS+1) * 512]
    char* ws = (char*)d_ws;
    int*   count   = (int*)ws;
    int*   srcList = (int*)(ws + 256);
    float* aS      = (float*)(ws + 4352);
    float* aD      = (float*)(ws + 20992);
    float* h_all   = (float*)(ws + 21504);

    long long avail = ((long long)ws_size - 21504) / (HDIM * (long long)sizeof(float)) - 1;
    int cap = CAPSLOTS;
    if (avail < cap) cap = (int)avail;
    if (cap < 1) cap = 1;

    hipMemsetAsync(count, 0, sizeof(int), stream);

    scan_edges_kernel<<<(E + 255) / 256, 256, 0, stream>>>(ei, E, tgt, count, srcList, cap);

    node_kernel<<<48, 256, 0, stream>>>(des, tw, npr, cpr,
                                        Wd, bd, Wt, bt, Wn, bn, Wc, bc,
                                        Wg, as_, ad_,
                                        tgt, count, cap, srcList,
                                        aS, aD, h_all);

    finalize_kernel<<<1, 512, 0, stream>>>(x, bg, Wo1, bo1, Wo2, bo2,
                                           count, cap, aS, aD, h_all,
                                           (float*)d_out);
}

// Round 2
// 27.959 us; speedup vs baseline: 1.5410x; 1.5410x over previous
//
#include <hip/hip_runtime.h>
#include <math.h>

#define HEADS 4
#define CDIM 128
#define HDIM 512   // HEADS*CDIM
#define FEAT 128
#define CAPSLOTS 1024

// ---------------- Kernel A: find edges with dst == target ----------------
__global__ void scan_edges_kernel(const int* __restrict__ ei, int E,
                                  const int* __restrict__ tgt_p,
                                  int* __restrict__ count,
                                  int* __restrict__ srcList, int cap) {
    int tgt = *tgt_p;
    int i = blockIdx.x * blockDim.x + threadIdx.x;
    if (i < E) {
        if (ei[E + i] == tgt) {                 // edge_index[1][i]
            int pos = atomicAdd(count, 1);
            if (pos < cap) srcList[pos] = ei[i]; // edge_index[0][i]
        }
    }
}

// ---------------- Kernel B1: per-slot 128-dim feature, fully parallel ----------------
// slot in [0,cnt): srcList nodes; slot == cnt: target (self-loop).
__global__ void feat_kernel(const float* __restrict__ des, const float* __restrict__ tw,
                            const float* __restrict__ npr, const float* __restrict__ cpr,
                            const float* __restrict__ Wd, const float* __restrict__ bd,
                            const float* __restrict__ Wt, const float* __restrict__ bt,
                            const float* __restrict__ Wn, const float* __restrict__ bn,
                            const float* __restrict__ Wc, const float* __restrict__ bc,
                            const int* __restrict__ tgt_p, const int* __restrict__ count, int cap,
                            const int* __restrict__ srcList,
                            float* __restrict__ feat_all) {
    __shared__ float sdes[768];
    __shared__ float stw[768];
    __shared__ float snp[8];
    __shared__ float part[256];

    int cnt = min(*count, cap);
    int tid = threadIdx.x;
    int j = tid & 31, ch = tid >> 5;   // 8 chunks x 32 outputs

    for (int slot = blockIdx.x; slot <= cnt; slot += gridDim.x) {
        int node = (slot == cnt) ? *tgt_p : srcList[slot];

        const float4* d4 = (const float4*)(des + (size_t)node * 768);
        const float4* t4 = (const float4*)(tw  + (size_t)node * 768);
        if (tid < 192) {
            ((float4*)sdes)[tid] = d4[tid];
            ((float4*)stw)[tid]  = t4[tid];
        } else if (tid < 197) {
            snp[tid - 192] = npr[node * 5 + (tid - 192)];
        } else if (tid == 197) {
            snp[5] = cpr[node];
        }
        __syncthreads();

        // des @ Wd : each output j summed by 8 threads over 96-element chunks
        {
            float p = 0.f;
            const float* w = Wd + (size_t)(ch * 96) * 32 + j;
            const float* s = sdes + ch * 96;
            #pragma unroll 8
            for (int k = 0; k < 96; ++k) p = fmaf(s[k], w[(size_t)k * 32], p);
            part[tid] = p;
        }
        __syncthreads();
        if (tid < 32) {
            float a = bd[tid];
            #pragma unroll
            for (int c = 0; c < 8; ++c) a += part[c * 32 + tid];
            feat_all[slot * FEAT + tid] = a > 0.f ? a : 0.01f * a;
        }
        __syncthreads();

        // tweet @ Wt
        {
            float p = 0.f;
            const float* w = Wt + (size_t)(ch * 96) * 32 + j;
            const float* s = stw + ch * 96;
            #pragma unroll 8
            for (int k = 0; k < 96; ++k) p = fmaf(s[k], w[(size_t)k * 32], p);
            part[tid] = p;
        }
        __syncthreads();
        if (tid < 32) {
            float a = bt[tid];
            #pragma unroll
            for (int c = 0; c < 8; ++c) a += part[c * 32 + tid];
            feat_all[slot * FEAT + 32 + tid] = a > 0.f ? a : 0.01f * a;
        } else if (tid < 64) {
            int jj = tid - 32;
            float a = bn[jj];
            #pragma unroll
            for (int k = 0; k < 5; ++k) a = fmaf(snp[k], Wn[k * 32 + jj], a);
            feat_all[slot * FEAT + 64 + jj] = a > 0.f ? a : 0.01f * a;
        } else if (tid < 96) {
            int jj = tid - 64;
            float a = fmaf(snp[5], Wc[jj], bc[jj]);
            feat_all[slot * FEAT + 96 + jj] = a > 0.f ? a : 0.01f * a;
        }
        __syncthreads();   // protect LDS before next slot
    }
}

// ---------------- Kernel B2: h = feat @ Wg per (slot, head) + src logits ----------------
__global__ void h_kernel(const float* __restrict__ Wg, const float* __restrict__ att_src,
                         const int* __restrict__ count, int cap,
                         const float* __restrict__ feat_all,
                         float* __restrict__ h_all, float* __restrict__ aS) {
    __shared__ float sfeat[FEAT];
    __shared__ float pr[256];

    int cnt = min(*count, cap);
    int npair = (cnt + 1) * HEADS;
    int tid = threadIdx.x;
    int c = tid & 127, kh = tid >> 7;   // 2 k-chunks of 64

    for (int pair = blockIdx.x; pair < npair; pair += gridDim.x) {
        int slot = pair >> 2, hd = pair & 3;
        if (tid < FEAT) sfeat[tid] = feat_all[slot * FEAT + tid];
        __syncthreads();

        float p = 0.f;
        const float* w = Wg + (size_t)(kh * 64) * HDIM + hd * CDIM + c;
        const float* s = sfeat + kh * 64;
        #pragma unroll 8
        for (int k = 0; k < 64; ++k) p = fmaf(s[k], w[(size_t)k * HDIM], p);
        pr[tid] = p;
        __syncthreads();

        if (tid < 128) {
            float hv = pr[tid] + pr[tid + 128];
            h_all[(size_t)slot * HDIM + hd * CDIM + tid] = hv;
            pr[tid] = hv * att_src[hd * CDIM + tid];
        }
        __syncthreads();
        if (tid < 64) {
            float v = pr[tid] + pr[tid + 64];
            #pragma unroll
            for (int off = 32; off > 0; off >>= 1) v += __shfl_down(v, off);
            if (tid == 0) aS[slot * HEADS + hd] = v;
        }
        __syncthreads();
    }
}

// ---------------- Kernel C: aD + softmax-aggregate + head-mean + MLP ----------------
__global__ void finalize_kernel(const float* __restrict__ x, const float* __restrict__ att_dst,
                                const float* __restrict__ bgat,
                                const float* __restrict__ Wo1, const float* __restrict__ bo1,
                                const float* __restrict__ Wo2, const float* __restrict__ bo2,
                                const int* __restrict__ count, int cap,
                                const float* __restrict__ aS, const float* __restrict__ h_all,
                                float* __restrict__ out) {
    __shared__ float pr[HDIM];
    __shared__ float sadv[HEADS];
    __shared__ float sout[HDIM];
    __shared__ float scomb[136];
    __shared__ float shmid[64];

    int cnt = min(*count, cap);
    int M = cnt + 1;
    int tid = threadIdx.x;          // 512
    int hd = tid >> 7, c = tid & 127;

    // aD[hd] = <h[target, hd, :], att_dst[hd, :]>
    pr[tid] = h_all[(size_t)cnt * HDIM + tid] * att_dst[tid];
    __syncthreads();
    if (c < 64) {
        float v = pr[hd * 128 + c] + pr[hd * 128 + c + 64];
        #pragma unroll
        for (int off = 32; off > 0; off >>= 1) v += __shfl_down(v, off);
        if (c == 0) sadv[hd] = v;
    }
    __syncthreads();

    float adv = sadv[hd];
    float m = -INFINITY;
    for (int s = 0; s < M; ++s) {
        float e = aS[s * HEADS + hd] + adv;
        e = e > 0.f ? e : 0.2f * e;      // leaky_relu slope 0.2
        m = fmaxf(m, e);
    }
    float denom = 0.f, acc = 0.f;
    for (int s = 0; s < M; ++s) {
        float e = aS[s * HEADS + hd] + adv;
        e = e > 0.f ? e : 0.2f * e;
        float ex = expf(e - m);
        denom += ex;
        acc = fmaf(ex, h_all[(size_t)s * HDIM + hd * CDIM + c], acc);
    }
    sout[tid] = acc / denom;
    __syncthreads();

    if (tid < 128) {
        scomb[tid] = (sout[tid] + sout[128 + tid] + sout[256 + tid] + sout[384 + tid]) * 0.25f
                     + bgat[tid];
    } else if (tid < 136) {
        scomb[tid] = x[tid - 128];
    }
    __syncthreads();

    if (tid < 64) {
        float a = bo1[tid];
        for (int k = 0; k < 136; ++k) a = fmaf(scomb[k], Wo1[k * 64 + tid], a);
        shmid[tid] = a > 0.f ? a : 0.f;
    }
    __syncthreads();
    if (tid < 5) {
        float a = bo2[tid];
        for (int k = 0; k < 64; ++k) a = fmaf(shmid[k], Wo2[k * 5 + tid], a);
        out[tid] = a;
    }
}

extern "C" void kernel_launch(void* const* d_in, const int* in_sizes, int n_in,
                              void* d_out, int out_size, void* d_ws, size_t ws_size,
                              hipStream_t stream) {
    const float* x    = (const float*)d_in[0];
    const float* des  = (const float*)d_in[1];
    const float* tw   = (const float*)d_in[2];
    const float* npr  = (const float*)d_in[3];
    const float* cpr  = (const float*)d_in[4];
    const int*   ei   = (const int*)d_in[5];     // [2, E] flat
    const int*   tgt  = (const int*)d_in[6];
    const float* Wd   = (const float*)d_in[7];   const float* bd  = (const float*)d_in[8];
    const float* Wt   = (const float*)d_in[9];   const float* bt  = (const float*)d_in[10];
    const float* Wn   = (const float*)d_in[11];  const float* bn  = (const float*)d_in[12];
    const float* Wc   = (const float*)d_in[13];  const float* bc  = (const float*)d_in[14];
    const float* Wg   = (const float*)d_in[15];
    const float* as_  = (const float*)d_in[16];  const float* ad_ = (const float*)d_in[17];
    const float* bg   = (const float*)d_in[18];
    const float* Wo1  = (const float*)d_in[19];  const float* bo1 = (const float*)d_in[20];
    const float* Wo2  = (const float*)d_in[21];  const float* bo2 = (const float*)d_in[22];

    const int E = in_sizes[5] / 2;

    // workspace layout: count | srcList[cap] | aS[(cap+1)*4] | feat[(cap+1)*128] | h[(cap+1)*512]
    const long long per = 4 + 16 + FEAT * 4 + HDIM * 4;   // bytes per slot = 2580
    long long avail = ((long long)ws_size - 512) / per - 1;
    int cap = CAPSLOTS;
    if (avail < cap) cap = (int)avail;
    if (cap < 1) cap = 1;

    char* ws = (char*)d_ws;
    int*   count    = (int*)ws;
    int*   srcList  = (int*)(ws + 512);
    float* aS       = (float*)(ws + 512 + (size_t)cap * 4);
    float* feat_all = aS + (size_t)(cap + 1) * HEADS;
    float* h_all    = feat_all + (size_t)(cap + 1) * FEAT;

    hipMemsetAsync(count, 0, sizeof(int), stream);

    scan_edges_kernel<<<(E + 511) / 512, 512, 0, stream>>>(ei, E, tgt, count, srcList, cap);

    feat_kernel<<<16, 256, 0, stream>>>(des, tw, npr, cpr,
                                        Wd, bd, Wt, bt, Wn, bn, Wc, bc,
                                        tgt, count, cap, srcList, feat_all);

    h_kernel<<<64, 256, 0, stream>>>(Wg, as_, count, cap, feat_all, h_all, aS);

    finalize_kernel<<<1, 512, 0, stream>>>(x, ad_, bg, Wo1, bo1, Wo2, bo2,
                                           count, cap, aS, h_all, (float*)d_out);
}